// Round 1
// 481.111 us; speedup vs baseline: 1.0006x; 1.0006x over previous
//
#include <hip/hip_runtime.h>
#include <hip/hip_bf16.h>

#define N_NODES 8192
#define NF      256
#define L2E     1.44269504088896341f

typedef __attribute__((ext_vector_type(8))) short short8;
typedef __attribute__((ext_vector_type(4))) short short4v;
typedef __attribute__((ext_vector_type(4))) float floatx4;

static __device__ __forceinline__ float bf2f(short s) {
    return __uint_as_float(((unsigned)(unsigned short)s) << 16);
}
static __device__ __forceinline__ short f2bf_rn(float f) {
    unsigned u = __float_as_uint(f) + 0x8000u;
    return (short)(u >> 16);
}
struct bfpair { short hi, lo; };
static __device__ __forceinline__ bfpair split_bf(float x) {
    bfpair p;
    p.hi = f2bf_rn(x);
    p.lo = f2bf_rn(x - bf2f(p.hi));
    return p;
}
// async global->LDS, 16B/lane, LDS dest = uniform base + lane*16
static __device__ __forceinline__ void async16(const void* g, void* l) {
    __builtin_amdgcn_global_load_lds(
        (const __attribute__((address_space(1))) unsigned*)g,
        (__attribute__((address_space(3))) unsigned*)l, 16, 0, 0);
}

// ---------------------------------------------------------------------------
// KX: split W (256x256 fp32) into bf16 hi/lo arrays, once.
// ---------------------------------------------------------------------------
__global__ __launch_bounds__(256) void kx_split(const float* __restrict__ W,
                                                short* __restrict__ Whi,
                                                short* __restrict__ Wlo) {
    #pragma unroll
    for (int e = 0; e < 4; ++e) {
        const int i = blockIdx.x * 1024 + e * 256 + threadIdx.x;
        bfpair p = split_bf(W[i]);
        Whi[i] = p.hi;
        Wlo[i] = p.lo;
    }
}

// ---------------------------------------------------------------------------
// K1: WhT[n][i] = sum_k X[i][k]*W[n][k] via hi/lo bf16 MFMA (fp32-accurate).
// Also emits per-cq partials of s_src/s_dst from fp32 accumulators.
// grid 256 (32 i-rows each) x 512 thr (8 waves = 2 rowhalf x 4 colquarter).
// X staged fp32 -> LDS (async16, 16B-chunk XOR swizzle), split in-register.
// ---------------------------------------------------------------------------
__global__ __launch_bounds__(512) void k1_gemm(const float* __restrict__ X,
                                               const short* __restrict__ Whi,
                                               const short* __restrict__ Wlo,
                                               const float* __restrict__ r,
                                               short* __restrict__ WhT,
                                               float* __restrict__ sp_src,
                                               float* __restrict__ sp_dst) {
    __shared__ float Xs[32 * 256];   // 32 KB; chunk slot = c ^ (row&7)

    const int tid = threadIdx.x;
    const int w = tid >> 6, lane = tid & 63;
    const int q = lane >> 4, m = lane & 15;
    const int rh = w >> 2, cq = w & 3;
    const int i_base = blockIdx.x * 32;

    // stage 32 rows of X (1 KB each); 4 instrs/wave
    #pragma unroll
    for (int v = 0; v < 4; ++v) {
        const int rowv = w * 4 + v;
        const int c = lane ^ (rowv & 7);
        async16(X + (size_t)(i_base + rowv) * NF + c * 4, &Xs[rowv * 256]);
    }
    __syncthreads();

    floatx4 acc[4] = {};
    const int xrow = rh * 16 + m;
    const int r7 = xrow & 7;
    #pragma unroll
    for (int ks = 0; ks < 8; ++ks) {
        const int c0 = ks * 8 + q * 2;
        float4 f0 = *(const float4*)(&Xs[xrow * 256 + ((c0 ^ r7) * 4)]);
        float4 f1 = *(const float4*)(&Xs[xrow * 256 + (((c0 + 1) ^ r7) * 4)]);
        const float xsv[8] = {f0.x, f0.y, f0.z, f0.w, f1.x, f1.y, f1.z, f1.w};
        short8 xh, xl;
        #pragma unroll
        for (int c = 0; c < 8; ++c) {
            bfpair p = split_bf(xsv[c]);
            xh[c] = p.hi; xl[c] = p.lo;
        }
        #pragma unroll
        for (int nt = 0; nt < 4; ++nt) {
            const int n = cq * 64 + nt * 16 + m;
            short8 wh = *(const short8*)(Whi + n * NF + ks * 32 + q * 8);
            short8 wl = *(const short8*)(Wlo + n * NF + ks * 32 + q * 8);
            acc[nt] = __builtin_amdgcn_mfma_f32_16x16x32_bf16(xh, wh, acc[nt], 0, 0, 0);
            acc[nt] = __builtin_amdgcn_mfma_f32_16x16x32_bf16(xl, wh, acc[nt], 0, 0, 0);
            acc[nt] = __builtin_amdgcn_mfma_f32_16x16x32_bf16(xh, wl, acc[nt], 0, 0, 0);
        }
    }

    // C/D layout: col = lane&15 (n), row = q*4 + reg (i)
    const int i0 = i_base + rh * 16 + q * 4;
    float vs[4] = {0.f, 0.f, 0.f, 0.f}, vd[4] = {0.f, 0.f, 0.f, 0.f};
    #pragma unroll
    for (int nt = 0; nt < 4; ++nt) {
        const int n = cq * 64 + nt * 16 + m;
        short4v v;
        #pragma unroll
        for (int r2 = 0; r2 < 4; ++r2) v[r2] = f2bf_rn(acc[nt][r2]);
        *(short4v*)(WhT + (size_t)n * N_NODES + i0) = v;
        const float rs = r[n], rd = r[NF + n];
        #pragma unroll
        for (int r2 = 0; r2 < 4; ++r2) {
            vs[r2] = fmaf(acc[nt][r2], rs, vs[r2]);
            vd[r2] = fmaf(acc[nt][r2], rd, vd[r2]);
        }
    }
    #pragma unroll
    for (int mask = 1; mask <= 8; mask <<= 1) {
        #pragma unroll
        for (int r2 = 0; r2 < 4; ++r2) {
            vs[r2] += __shfl_xor(vs[r2], mask);
            vd[r2] += __shfl_xor(vd[r2], mask);
        }
    }
    if (m == 0) {
        #pragma unroll
        for (int r2 = 0; r2 < 4; ++r2) {
            sp_src[cq * N_NODES + i0 + r2] = vs[r2];
            sp_dst[cq * N_NODES + i0 + r2] = vd[r2];
        }
    }
}

// ---------------------------------------------------------------------------
// K2: sum 4 partials -> s_src/s_dst; per-block max(s_dst) -> pmax[32]
// ---------------------------------------------------------------------------
__global__ __launch_bounds__(256) void k2_sv(const float* __restrict__ sp_src,
                                             const float* __restrict__ sp_dst,
                                             float* __restrict__ s_src,
                                             float* __restrict__ s_dst,
                                             float* __restrict__ pmax) {
    __shared__ float red[256];
    const int tid = threadIdx.x;
    const int i = blockIdx.x * 256 + tid;
    float ss = 0.f, sd = 0.f;
    #pragma unroll
    for (int nb = 0; nb < 4; ++nb) {
        ss += sp_src[nb * N_NODES + i];
        sd += sp_dst[nb * N_NODES + i];
    }
    s_src[i] = ss;
    s_dst[i] = sd;
    red[tid] = sd;
    __syncthreads();
    for (int off = 128; off > 0; off >>= 1) {
        if (tid < off) red[tid] = fmaxf(red[tid], red[tid + off]);
        __syncthreads();
    }
    if (tid == 0) pmax[blockIdx.x] = red[0];
}

// ---------------------------------------------------------------------------
// K4: fused masked-softmax attention + PV MFMA + exact GELU.
// grid 256 x 1024 thr (16 waves = 2 rowhalf x 2 colhalf x 4 jquarter).
// NEW: B double-buffered as 2 x [256 n][128 j] bf16 (2 x 64 KB).
// Per 128-j step: issue next-tile stage (4 async16/wave) + next A/t register
// prefetch at TOP, compute current tile, then ONE __syncthreads() whose
// implicit vmcnt(0) drain lands after the compute phase -> stage latency and
// A HBM latency are hidden under MFMA/VALU instead of exposed.
// 16B-chunk XOR swizzle (slot = chunk ^ (n&7)) applied on the pre-swizzled
// GLOBAL source (linear LDS dest per global_load_lds rules) and mirrored on
// the ds_read side -> bank-quad uniform.
// ---------------------------------------------------------------------------
static __device__ __forceinline__ void pgroup(const int4 a, const floatx4 t,
                                              const float s_i, const float d_i,
                                              float* p) {
    const int av[4] = {a.x, a.y, a.z, a.w};
    #pragma unroll
    for (int c = 0; c < 4; ++c) {
        float sum = s_i + t[c];
        float lr  = fmaxf(sum, 0.2f * sum);
        float pp  = __builtin_amdgcn_exp2f(fmaf(lr, L2E, d_i));
        p[c] = (av[c] != 0) ? pp : 0.0f;
    }
}

__global__ __launch_bounds__(1024) void k4_attn(const int* __restrict__ Adj,
                                                const short* __restrict__ WhT,
                                                const float* __restrict__ s_dst,
                                                const float* __restrict__ s_src,
                                                const float* __restrict__ pmax,
                                                float* __restrict__ out) {
    __shared__ union {
        short B[2][256][128];         // [buf][n][128 j-shorts]; 16B slot = c^(n&7)
        float red[16 * 8 * 4 * 64];   // [wave][nt][reg][lane]
    } sm;
    __shared__ float denred[128];

    const int tid = threadIdx.x;
    const int w = tid >> 6, lane = tid & 63;
    const int q = lane >> 4, m = lane & 15;
    const int rh = w >> 3, ch = (w >> 2) & 1, jq = w & 3;
    const int i0 = blockIdx.x * 32;
    const int row = i0 + rh * 16 + m;

    float M = pmax[0];
    #pragma unroll
    for (int b = 1; b < 32; ++b) M = fmaxf(M, pmax[b]);
    const float s_i = s_src[row];
    const float e0 = s_i + M;
    const float d_i = -fmaxf(e0, 0.2f * e0) * L2E;   // -c_i*log2e, c_i >= row max

    // ---- B staging source pointers: wave stages n-rows [w*16, w*16+16) ----
    // lane l -> n_local = l>>4, stored slot = l&15; logical chunk = slot^(n&7)
    const int nloc = lane >> 4;
    const int scl = lane & 15;
    const short* gB[4];
    #pragma unroll
    for (int v = 0; v < 4; ++v) {
        const int n = w * 16 + v * 4 + nloc;
        const int c = scl ^ (n & 7);
        gB[v] = WhT + (size_t)n * N_NODES + c * 8;
    }

    // ---- A / t pointers (per lane): 8 j per lane per step ----
    const int* Ap = Adj + (size_t)row * N_NODES + jq * 32 + q * 8;
    const float* tp = s_dst + jq * 32 + q * 8;

    floatx4 acc[8];
    #pragma unroll
    for (int nt = 0; nt < 8; ++nt) acc[nt] = (floatx4){0.f, 0.f, 0.f, 0.f};
    float den = 0.f;

    // prologue: stage step 0 into buf 0, prefetch A(0)/t(0)
    #pragma unroll
    for (int v = 0; v < 4; ++v)
        async16(gB[v], &sm.B[0][w * 16 + v * 4][0]);
    int4 a0 = *(const int4*)(Ap);
    int4 a1 = *(const int4*)(Ap + 4);
    floatx4 t0 = *(const floatx4*)(tp);
    floatx4 t1 = *(const floatx4*)(tp + 4);
    __syncthreads();

    for (int s = 0; s < 64; ++s) {
        const int cur = s & 1;

        // issue next tile's staging into the other buffer (free since the
        // end-of-previous-step barrier; drained by this step's end barrier)
        if (s < 63) {
            const int go = (s + 1) * 128;
            #pragma unroll
            for (int v = 0; v < 4; ++v)
                async16(gB[v] + go, &sm.B[cur ^ 1][w * 16 + v * 4][0]);
        }
        // prefetch next step's A (HBM) and t (L2-hot) into registers
        const int offn = ((s < 63) ? (s + 1) : s) * 128;
        int4 na0 = *(const int4*)(Ap + offn);
        int4 na1 = *(const int4*)(Ap + offn + 4);
        floatx4 nt0 = *(const floatx4*)(tp + offn);
        floatx4 nt1 = *(const floatx4*)(tp + offn + 4);

        // P for this step: 8 j per lane (j = s*128 + jq*32 + q*8 + c)
        float p[8];
        pgroup(a0, t0, s_i, d_i, p);
        pgroup(a1, t1, s_i, d_i, p + 4);

        short8 af;
        #pragma unroll
        for (int c = 0; c < 8; ++c) af[c] = f2bf_rn(p[c]);
        #pragma unroll
        for (int c = 0; c < 8; ++c) den += p[c];

        // PV: 8 MFMAs, k = this wave's 32-j slice
        const short* Bb = &sm.B[cur][0][0];
        #pragma unroll
        for (int nt = 0; nt < 8; ++nt) {
            const int n = ch * 128 + nt * 16 + m;
            const int sc = (jq * 4 + q) ^ (n & 7);
            short8 b0 = *(const short8*)(Bb + n * 128 + sc * 8);
            acc[nt] = __builtin_amdgcn_mfma_f32_16x16x32_bf16(af, b0, acc[nt], 0, 0, 0);
        }

        a0 = na0; a1 = na1; t0 = nt0; t1 = nt1;
        __syncthreads();     // implicit vmcnt(0): next tile + A prefetch landed
    }

    // ---- epilogue: reduce den and acc across the 4 jq waves ----
    den += __shfl_xor(den, 16);
    den += __shfl_xor(den, 32);
    if (ch == 0 && lane < 16) denred[rh * 64 + jq * 16 + lane] = den;
    #pragma unroll
    for (int nt = 0; nt < 8; ++nt)
        #pragma unroll
        for (int rg = 0; rg < 4; ++rg)
            sm.red[((w * 8 + nt) * 4 + rg) * 64 + lane] = acc[nt][rg];
    __syncthreads();

    float invd[4];
    #pragma unroll
    for (int rg = 0; rg < 4; ++rg) {
        const int rr = rh * 64 + q * 4 + rg;
        invd[rg] = 1.0f / fmaxf(denred[rr] + denred[rr + 16] +
                                denred[rr + 32] + denred[rr + 48], 1e-30f);
    }
    const int wb = rh * 8 + ch * 4;
    #pragma unroll
    for (int t2 = 0; t2 < 2; ++t2) {
        const int nt = jq * 2 + t2;
        #pragma unroll
        for (int rg = 0; rg < 4; ++rg) {
            float v = sm.red[(((wb + 0) * 8 + nt) * 4 + rg) * 64 + lane]
                    + sm.red[(((wb + 1) * 8 + nt) * 4 + rg) * 64 + lane]
                    + sm.red[(((wb + 2) * 8 + nt) * 4 + rg) * 64 + lane]
                    + sm.red[(((wb + 3) * 8 + nt) * 4 + rg) * 64 + lane];
            float x = v * invd[rg];
            float g = 0.5f * x * (1.0f + erff(x * 0.70710678118f)); // exact GELU
            out[(size_t)(i0 + rh * 16 + q * 4 + rg) * NF + ch * 128 + nt * 16 + m] = g;
        }
    }
}

// ---------------------------------------------------------------------------
extern "C" void kernel_launch(void* const* d_in, const int* in_sizes, int n_in,
                              void* d_out, int out_size, void* d_ws, size_t ws_size,
                              hipStream_t stream) {
    const float* X = (const float*)d_in[0];   // fp32 8192x256
    const int*   A = (const int*)d_in[1];     // int32 8192x8192
    const float* W = (const float*)d_in[2];   // fp32 256x256
    const float* r = (const float*)d_in[3];   // fp32 512
    float* out = (float*)d_out;

    // ws: WhT bf16 4MB | Whi 128K | Wlo 128K | sp_src 128K | sp_dst 128K |
    //     s_src 32K | s_dst 32K | pmax 128B
    char* wsp = (char*)d_ws;
    short* WhT    = (short*)wsp;                    wsp += (size_t)NF * N_NODES * 2;
    short* Whi    = (short*)wsp;                    wsp += NF * NF * 2;
    short* Wlo    = (short*)wsp;                    wsp += NF * NF * 2;
    float* sp_src = (float*)wsp;                    wsp += 4 * N_NODES * 4;
    float* sp_dst = (float*)wsp;                    wsp += 4 * N_NODES * 4;
    float* s_src  = (float*)wsp;                    wsp += N_NODES * 4;
    float* s_dst  = (float*)wsp;                    wsp += N_NODES * 4;
    float* pmax   = (float*)wsp;

    kx_split<<<64, 256, 0, stream>>>(W, Whi, Wlo);
    k1_gemm<<<256, 512, 0, stream>>>(X, Whi, Wlo, r, WhT, sp_src, sp_dst);
    k2_sv<<<32, 256, 0, stream>>>(sp_src, sp_dst, s_src, s_dst, pmax);
    k4_attn<<<256, 1024, 0, stream>>>(A, WhT, s_dst, s_src, pmax, out);
}

// Round 3
// 478.988 us; speedup vs baseline: 1.0050x; 1.0044x over previous
//
#include <hip/hip_runtime.h>
#include <hip/hip_bf16.h>

#define N_NODES 8192
#define NF      256
#define L2E     1.44269504088896341f

typedef __attribute__((ext_vector_type(8))) short short8;
typedef __attribute__((ext_vector_type(4))) short short4v;
typedef __attribute__((ext_vector_type(4))) float floatx4;

static __device__ __forceinline__ float bf2f(short s) {
    return __uint_as_float(((unsigned)(unsigned short)s) << 16);
}
static __device__ __forceinline__ short f2bf_rn(float f) {
    unsigned u = __float_as_uint(f) + 0x8000u;
    return (short)(u >> 16);
}
struct bfpair { short hi, lo; };
static __device__ __forceinline__ bfpair split_bf(float x) {
    bfpair p;
    p.hi = f2bf_rn(x);
    p.lo = f2bf_rn(x - bf2f(p.hi));
    return p;
}
// async global->LDS, 16B/lane, LDS dest = uniform base + lane*16
static __device__ __forceinline__ void async16(const void* g, void* l) {
    __builtin_amdgcn_global_load_lds(
        (const __attribute__((address_space(1))) unsigned*)g,
        (__attribute__((address_space(3))) unsigned*)l, 16, 0, 0);
}

// ---------------------------------------------------------------------------
// KX: split W (256x256 fp32) into bf16 hi/lo arrays, once.
// ---------------------------------------------------------------------------
__global__ __launch_bounds__(256) void kx_split(const float* __restrict__ W,
                                                short* __restrict__ Whi,
                                                short* __restrict__ Wlo) {
    #pragma unroll
    for (int e = 0; e < 4; ++e) {
        const int i = blockIdx.x * 1024 + e * 256 + threadIdx.x;
        bfpair p = split_bf(W[i]);
        Whi[i] = p.hi;
        Wlo[i] = p.lo;
    }
}

// ---------------------------------------------------------------------------
// K1: WhT[n][i] = sum_k X[i][k]*W[n][k] via hi/lo bf16 MFMA (fp32-accurate).
// Also emits per-cq partials of s_src/s_dst from fp32 accumulators.
// grid 256 (32 i-rows each) x 512 thr (8 waves = 2 rowhalf x 4 colquarter).
// X staged fp32 -> LDS (async16, 16B-chunk XOR swizzle), split in-register.
// ---------------------------------------------------------------------------
__global__ __launch_bounds__(512) void k1_gemm(const float* __restrict__ X,
                                               const short* __restrict__ Whi,
                                               const short* __restrict__ Wlo,
                                               const float* __restrict__ r,
                                               short* __restrict__ WhT,
                                               float* __restrict__ sp_src,
                                               float* __restrict__ sp_dst) {
    __shared__ float Xs[32 * 256];   // 32 KB; chunk slot = c ^ (row&7)

    const int tid = threadIdx.x;
    const int w = tid >> 6, lane = tid & 63;
    const int q = lane >> 4, m = lane & 15;
    const int rh = w >> 2, cq = w & 3;
    const int i_base = blockIdx.x * 32;

    // stage 32 rows of X (1 KB each); 4 instrs/wave
    #pragma unroll
    for (int v = 0; v < 4; ++v) {
        const int rowv = w * 4 + v;
        const int c = lane ^ (rowv & 7);
        async16(X + (size_t)(i_base + rowv) * NF + c * 4, &Xs[rowv * 256]);
    }
    __syncthreads();

    floatx4 acc[4] = {};
    const int xrow = rh * 16 + m;
    const int r7 = xrow & 7;
    #pragma unroll
    for (int ks = 0; ks < 8; ++ks) {
        const int c0 = ks * 8 + q * 2;
        float4 f0 = *(const float4*)(&Xs[xrow * 256 + ((c0 ^ r7) * 4)]);
        float4 f1 = *(const float4*)(&Xs[xrow * 256 + (((c0 + 1) ^ r7) * 4)]);
        const float xsv[8] = {f0.x, f0.y, f0.z, f0.w, f1.x, f1.y, f1.z, f1.w};
        short8 xh, xl;
        #pragma unroll
        for (int c = 0; c < 8; ++c) {
            bfpair p = split_bf(xsv[c]);
            xh[c] = p.hi; xl[c] = p.lo;
        }
        #pragma unroll
        for (int nt = 0; nt < 4; ++nt) {
            const int n = cq * 64 + nt * 16 + m;
            short8 wh = *(const short8*)(Whi + n * NF + ks * 32 + q * 8);
            short8 wl = *(const short8*)(Wlo + n * NF + ks * 32 + q * 8);
            acc[nt] = __builtin_amdgcn_mfma_f32_16x16x32_bf16(xh, wh, acc[nt], 0, 0, 0);
            acc[nt] = __builtin_amdgcn_mfma_f32_16x16x32_bf16(xl, wh, acc[nt], 0, 0, 0);
            acc[nt] = __builtin_amdgcn_mfma_f32_16x16x32_bf16(xh, wl, acc[nt], 0, 0, 0);
        }
    }

    // C/D layout: col = lane&15 (n), row = q*4 + reg (i)
    const int i0 = i_base + rh * 16 + q * 4;
    float vs[4] = {0.f, 0.f, 0.f, 0.f}, vd[4] = {0.f, 0.f, 0.f, 0.f};
    #pragma unroll
    for (int nt = 0; nt < 4; ++nt) {
        const int n = cq * 64 + nt * 16 + m;
        short4v v;
        #pragma unroll
        for (int r2 = 0; r2 < 4; ++r2) v[r2] = f2bf_rn(acc[nt][r2]);
        *(short4v*)(WhT + (size_t)n * N_NODES + i0) = v;
        const float rs = r[n], rd = r[NF + n];
        #pragma unroll
        for (int r2 = 0; r2 < 4; ++r2) {
            vs[r2] = fmaf(acc[nt][r2], rs, vs[r2]);
            vd[r2] = fmaf(acc[nt][r2], rd, vd[r2]);
        }
    }
    #pragma unroll
    for (int mask = 1; mask <= 8; mask <<= 1) {
        #pragma unroll
        for (int r2 = 0; r2 < 4; ++r2) {
            vs[r2] += __shfl_xor(vs[r2], mask);
            vd[r2] += __shfl_xor(vd[r2], mask);
        }
    }
    if (m == 0) {
        #pragma unroll
        for (int r2 = 0; r2 < 4; ++r2) {
            sp_src[cq * N_NODES + i0 + r2] = vs[r2];
            sp_dst[cq * N_NODES + i0 + r2] = vd[r2];
        }
    }
}

// ---------------------------------------------------------------------------
// K2: sum 4 partials -> s_src/s_dst; per-block max(s_dst) -> pmax[32]
// ---------------------------------------------------------------------------
__global__ __launch_bounds__(256) void k2_sv(const float* __restrict__ sp_src,
                                             const float* __restrict__ sp_dst,
                                             float* __restrict__ s_src,
                                             float* __restrict__ s_dst,
                                             float* __restrict__ pmax) {
    __shared__ float red[256];
    const int tid = threadIdx.x;
    const int i = blockIdx.x * 256 + tid;
    float ss = 0.f, sd = 0.f;
    #pragma unroll
    for (int nb = 0; nb < 4; ++nb) {
        ss += sp_src[nb * N_NODES + i];
        sd += sp_dst[nb * N_NODES + i];
    }
    s_src[i] = ss;
    s_dst[i] = sd;
    red[tid] = sd;
    __syncthreads();
    for (int off = 128; off > 0; off >>= 1) {
        if (tid < off) red[tid] = fmaxf(red[tid], red[tid + off]);
        __syncthreads();
    }
    if (tid == 0) pmax[blockIdx.x] = red[0];
}

// ---------------------------------------------------------------------------
// K4: fused masked-softmax attention + PV MFMA + exact GELU.
// grid 256 x 1024 thr (16 waves = 2 rowhalf x 2 colhalf x 4 jquarter).
// B double-buffered as 2 x [256 n][128 j] bf16 (2 x 64 KB).
// T3/T4/T5 schedule (RESUBMIT of round 2 — infra failure, kernel unmeasured):
// per step, issue order pinned with sched_barrier(0):
//   [4 stage async16] -> [4 A/t prefetch loads] -> compute -> MFMA cluster
//   under s_setprio(1) -> s_waitcnt vmcnt(4) (drains exactly the 4 oldest
//   vmem ops = this step's stage DMAs; the 4 A/t HBM prefetches stay IN
//   FLIGHT across the barrier) -> raw s_barrier.
// No vmcnt(0) drain anywhere in the main loop (m218: counted-vs-drain0 =
// +38-73%). Branchless: s=63 wraps stage/prefetch to step 0 (dummy).
// Hardened: "memory" clobber on the counted waitcnt.
// ---------------------------------------------------------------------------
static __device__ __forceinline__ void pgroup(const int4 a, const floatx4 t,
                                              const float s_i, const float d_i,
                                              float* p) {
    const int av[4] = {a.x, a.y, a.z, a.w};
    #pragma unroll
    for (int c = 0; c < 4; ++c) {
        float sum = s_i + t[c];
        float lr  = fmaxf(sum, 0.2f * sum);
        float pp  = __builtin_amdgcn_exp2f(fmaf(lr, L2E, d_i));
        p[c] = (av[c] != 0) ? pp : 0.0f;
    }
}

__global__ __launch_bounds__(1024) void k4_attn(const int* __restrict__ Adj,
                                                const short* __restrict__ WhT,
                                                const float* __restrict__ s_dst,
                                                const float* __restrict__ s_src,
                                                const float* __restrict__ pmax,
                                                float* __restrict__ out) {
    __shared__ union {
        short B[2][256][128];         // [buf][n][128 j-shorts]; 16B slot = c^(n&7)
        float red[16 * 8 * 4 * 64];   // [wave][nt][reg][lane]
    } sm;
    __shared__ float denred[128];

    const int tid = threadIdx.x;
    const int w = tid >> 6, lane = tid & 63;
    const int q = lane >> 4, m = lane & 15;
    const int rh = w >> 3, ch = (w >> 2) & 1, jq = w & 3;
    const int i0 = blockIdx.x * 32;
    const int row = i0 + rh * 16 + m;

    float M = pmax[0];
    #pragma unroll
    for (int b = 1; b < 32; ++b) M = fmaxf(M, pmax[b]);
    const float s_i = s_src[row];
    const float e0 = s_i + M;
    const float d_i = -fmaxf(e0, 0.2f * e0) * L2E;   // -c_i*log2e, c_i >= row max

    // ---- B staging source pointers: wave stages n-rows [w*16, w*16+16) ----
    // lane l -> n_local = l>>4, stored slot = l&15; logical chunk = slot^(n&7)
    const int nloc = lane >> 4;
    const int scl = lane & 15;
    const short* gB[4];
    #pragma unroll
    for (int v = 0; v < 4; ++v) {
        const int n = w * 16 + v * 4 + nloc;
        const int c = scl ^ (n & 7);
        gB[v] = WhT + (size_t)n * N_NODES + c * 8;
    }

    // ---- A / t pointers (per lane): 8 j per lane per step ----
    const int* Ap = Adj + (size_t)row * N_NODES + jq * 32 + q * 8;
    const float* tp = s_dst + jq * 32 + q * 8;

    floatx4 acc[8];
    #pragma unroll
    for (int nt = 0; nt < 8; ++nt) acc[nt] = (floatx4){0.f, 0.f, 0.f, 0.f};
    float den = 0.f;

    // prologue: stage step 0 into buf 0, prefetch A(0)/t(0)
    #pragma unroll
    for (int v = 0; v < 4; ++v)
        async16(gB[v], &sm.B[0][w * 16 + v * 4][0]);
    int4 a0 = *(const int4*)(Ap);
    int4 a1 = *(const int4*)(Ap + 4);
    floatx4 t0 = *(const floatx4*)(tp);
    floatx4 t1 = *(const floatx4*)(tp + 4);
    __syncthreads();

    for (int s = 0; s < 64; ++s) {
        const int cur = s & 1;

        // 1) stage next tile into other buffer (the 4 OLDEST vmem ops)
        short* dstb = &sm.B[cur ^ 1][0][0];
        const int go = ((s + 1) & 63) * 128;
        #pragma unroll
        for (int v = 0; v < 4; ++v)
            async16(gB[v] + go, dstb + (w * 16 + v * 4) * 128);
        __builtin_amdgcn_sched_barrier(0);

        // 2) prefetch next step's A (HBM) and t (L2-hot) into registers
        int4 na0 = *(const int4*)(Ap + go);
        int4 na1 = *(const int4*)(Ap + go + 4);
        floatx4 nt0 = *(const floatx4*)(tp + go);
        floatx4 nt1 = *(const floatx4*)(tp + go + 4);
        __builtin_amdgcn_sched_barrier(0);

        // 3) P for this step: 8 j per lane (j = s*128 + jq*32 + q*8 + c)
        float p[8];
        pgroup(a0, t0, s_i, d_i, p);
        pgroup(a1, t1, s_i, d_i, p + 4);

        short8 af;
        #pragma unroll
        for (int c = 0; c < 8; ++c) af[c] = f2bf_rn(p[c]);
        #pragma unroll
        for (int c = 0; c < 8; ++c) den += p[c];

        // 4) PV: 8 MFMAs, k = this wave's 32-j slice
        const short* Bb = &sm.B[cur][0][0];
        __builtin_amdgcn_s_setprio(1);
        #pragma unroll
        for (int nt = 0; nt < 8; ++nt) {
            const int n = ch * 128 + nt * 16 + m;
            const int sc = (jq * 4 + q) ^ (n & 7);
            short8 b0 = *(const short8*)(Bb + n * 128 + sc * 8);
            acc[nt] = __builtin_amdgcn_mfma_f32_16x16x32_bf16(af, b0, acc[nt], 0, 0, 0);
        }
        __builtin_amdgcn_s_setprio(0);

        // 5) counted wait: drain ONLY the 4 stage DMAs; A/t stay in flight
        __builtin_amdgcn_sched_barrier(0);
        asm volatile("s_waitcnt vmcnt(4)" ::: "memory");
        __builtin_amdgcn_s_barrier();

        a0 = na0; a1 = na1; t0 = nt0; t1 = nt1;
    }

    // ---- epilogue: reduce den and acc across the 4 jq waves ----
    den += __shfl_xor(den, 16);
    den += __shfl_xor(den, 32);
    if (ch == 0 && lane < 16) denred[rh * 64 + jq * 16 + lane] = den;
    #pragma unroll
    for (int nt = 0; nt < 8; ++nt)
        #pragma unroll
        for (int rg = 0; rg < 4; ++rg)
            sm.red[((w * 8 + nt) * 4 + rg) * 64 + lane] = acc[nt][rg];
    __syncthreads();

    float invd[4];
    #pragma unroll
    for (int rg = 0; rg < 4; ++rg) {
        const int rr = rh * 64 + q * 4 + rg;
        invd[rg] = 1.0f / fmaxf(denred[rr] + denred[rr + 16] +
                                denred[rr + 32] + denred[rr + 48], 1e-30f);
    }
    const int wb = rh * 8 + ch * 4;
    #pragma unroll
    for (int t2 = 0; t2 < 2; ++t2) {
        const int nt = jq * 2 + t2;
        #pragma unroll
        for (int rg = 0; rg < 4; ++rg) {
            float v = sm.red[(((wb + 0) * 8 + nt) * 4 + rg) * 64 + lane]
                    + sm.red[(((wb + 1) * 8 + nt) * 4 + rg) * 64 + lane]
                    + sm.red[(((wb + 2) * 8 + nt) * 4 + rg) * 64 + lane]
                    + sm.red[(((wb + 3) * 8 + nt) * 4 + rg) * 64 + lane];
            float x = v * invd[rg];
            float g = 0.5f * x * (1.0f + erff(x * 0.70710678118f)); // exact GELU
            out[(size_t)(i0 + rh * 16 + q * 4 + rg) * NF + ch * 128 + nt * 16 + m] = g;
        }
    }
}

// ---------------------------------------------------------------------------
extern "C" void kernel_launch(void* const* d_in, const int* in_sizes, int n_in,
                              void* d_out, int out_size, void* d_ws, size_t ws_size,
                              hipStream_t stream) {
    const float* X = (const float*)d_in[0];   // fp32 8192x256
    const int*   A = (const int*)d_in[1];     // int32 8192x8192
    const float* W = (const float*)d_in[2];   // fp32 256x256
    const float* r = (const float*)d_in[3];   // fp32 512
    float* out = (float*)d_out;

    // ws: WhT bf16 4MB | Whi 128K | Wlo 128K | sp_src 128K | sp_dst 128K |
    //     s_src 32K | s_dst 32K | pmax 128B
    char* wsp = (char*)d_ws;
    short* WhT    = (short*)wsp;                    wsp += (size_t)NF * N_NODES * 2;
    short* Whi    = (short*)wsp;                    wsp += NF * NF * 2;
    short* Wlo    = (short*)wsp;                    wsp += NF * NF * 2;
    float* sp_src = (float*)wsp;                    wsp += 4 * N_NODES * 4;
    float* sp_dst = (float*)wsp;                    wsp += 4 * N_NODES * 4;
    float* s_src  = (float*)wsp;                    wsp += N_NODES * 4;
    float* s_dst  = (float*)wsp;                    wsp += N_NODES * 4;
    float* pmax   = (float*)wsp;

    kx_split<<<64, 256, 0, stream>>>(W, Whi, Wlo);
    k1_gemm<<<256, 512, 0, stream>>>(X, Whi, Wlo, r, WhT, sp_src, sp_dst);
    k2_sv<<<32, 256, 0, stream>>>(sp_src, sp_dst, s_src, s_dst, pmax);
    k4_attn<<<256, 1024, 0, stream>>>(A, WhT, s_dst, s_src, pmax, out);
}